// Round 6
// baseline (339.367 us; speedup 1.0000x reference)
//
#include <hip/hip_runtime.h>

#define N_NODES 100000
#define D_SRC 128
#define D_OUT 256
#define K_DIM 256   // D_DST + D_SRC
#define CAP 32      // bucket capacity per node (Poisson(6): P(deg>32) ~ 1e-15)
#define OVF_CAP 2048
#define PADA 136    // LDS A row stride in bf16 elems (272 B = 17 banks*4 -> 2-way free)

typedef __attribute__((ext_vector_type(8))) short short8;
typedef __attribute__((ext_vector_type(4))) float float4v;

__device__ inline unsigned short f2bf(float f) {
    unsigned int u = __float_as_uint(f);
    u += 0x7FFF + ((u >> 16) & 1);   // round-to-nearest-even
    return (unsigned short)(u >> 16);
}
__device__ inline float bf_lo(unsigned int u) { return __uint_as_float(u << 16); }
__device__ inline float bf_hi(unsigned int u) { return __uint_as_float(u & 0xFFFF0000u); }

// ---------------------------------------------------------------------------
// Kernel 1: grid-fused bucket (latency-bound atomics) + bf16 packs (BW-bound).
// Blocks [0, eblocks): bucket edges by dst.
// Blocks [eblocks, ...): pack x_src, x_dst, W to bf16 (one float4 per thread).
// ---------------------------------------------------------------------------
__global__ __launch_bounds__(256) void bucket_pack_kernel(
    const int*   __restrict__ ei,      // [2, E]
    const float* __restrict__ x_src,
    const float* __restrict__ x_dst,
    const float* __restrict__ W,
    int* __restrict__ deg,             // [N] (pre-zeroed)
    int* __restrict__ ovf_cnt,         // [1] (pre-zeroed)
    int* __restrict__ ovf,             // [OVF_CAP*2]
    int* __restrict__ bucket,          // [N*CAP]
    unsigned short* __restrict__ xsb,  // [N,128] bf16
    unsigned short* __restrict__ xdb,  // [N,128] bf16
    unsigned short* __restrict__ Wb,   // [256,256] bf16
    int n_edges, int eblocks)
{
    if ((int)blockIdx.x < eblocks) {
        int e = blockIdx.x * 256 + threadIdx.x;
        if (e >= n_edges) return;
        int s = ei[e];
        int d = ei[n_edges + e];
        int pos = atomicAdd(deg + d, 1);
        if (pos < CAP) {
            bucket[(size_t)d * CAP + pos] = s;
        } else {
            int o = atomicAdd(ovf_cnt, 1);
            if (o < OVF_CAP) { ovf[2 * o] = s; ovf[2 * o + 1] = d; }
        }
    } else {
        const int NF = N_NODES * (D_SRC / 4);          // 3,200,000 float4s
        const int WF = (D_OUT * K_DIM) / 4;            // 16,384 float4s
        int i = (blockIdx.x - eblocks) * 256 + threadIdx.x;
        const float* src; unsigned short* dst; int j;
        if (i < NF)          { src = x_src; dst = xsb; j = i; }
        else if (i < 2 * NF) { src = x_dst; dst = xdb; j = i - NF; }
        else                 { j = i - 2 * NF; if (j >= WF) return; src = W; dst = Wb; }
        float4 v = ((const float4*)src)[j];
        ushort4 o;
        o.x = f2bf(v.x); o.y = f2bf(v.y); o.z = f2bf(v.z); o.w = f2bf(v.w);
        ((ushort4*)dst)[j] = o;
    }
}

// ---------------------------------------------------------------------------
// Kernel 2: fused gather + bf16-MFMA GEMM.
// Phase 1: each wave gathers 16 nodes' bf16 means into LDS As[64][PADA].
// Phase 2: out = relu([xdb | As] @ Wb^T + b); A-xdst from global bf16,
//          A-agg from LDS, B from L2-hot Wb. LDS reused for coalesced
//          epilogue stores (exact size match, barrier-separated).
// ---------------------------------------------------------------------------
__global__ __launch_bounds__(256) void fused_gather_gemm_kernel(
    const unsigned short* __restrict__ xsb,   // [N,128] bf16
    const unsigned short* __restrict__ xdb,   // [N,128] bf16
    const unsigned short* __restrict__ Wb,    // [256,256] bf16
    const float* __restrict__ bias,           // [256]
    const int*   __restrict__ deg,            // [N]
    const int*   __restrict__ bucket,         // [N*CAP]
    const int*   __restrict__ ovf_cnt,        // [1]
    const int*   __restrict__ ovf,            // [OVF_CAP*2]
    float*       __restrict__ out)            // [N,256] fp32
{
    __shared__ __align__(16) unsigned short AsU[64 * PADA];   // 17408 B

    int t = threadIdx.x;
    int wave = t >> 6;
    int lane = t & 63;
    int m0 = blockIdx.x * 64;

    // ---- phase 1: gather means for rows wave*16 .. wave*16+15 ----
    for (int ni = 0; ni < 16; ++ni) {
        int nrow = wave * 16 + ni;
        int node = m0 + nrow;
        unsigned int packed = 0;
        if (node < N_NODES) {
            int dtot = deg[node];
            int n = (dtot < CAP) ? dtot : CAP;
            int idx = bucket[(size_t)node * CAP + (lane & 31)];
            float ax = 0.f, ay = 0.f;
            int i = 0;
            for (; i + 4 <= n; i += 4) {
                int s0 = __shfl(idx, i);
                int s1 = __shfl(idx, i + 1);
                int s2 = __shfl(idx, i + 2);
                int s3 = __shfl(idx, i + 3);
                unsigned int u0 = ((const unsigned int*)(xsb + (size_t)s0 * D_SRC))[lane];
                unsigned int u1 = ((const unsigned int*)(xsb + (size_t)s1 * D_SRC))[lane];
                unsigned int u2 = ((const unsigned int*)(xsb + (size_t)s2 * D_SRC))[lane];
                unsigned int u3 = ((const unsigned int*)(xsb + (size_t)s3 * D_SRC))[lane];
                ax += bf_lo(u0) + bf_lo(u1) + bf_lo(u2) + bf_lo(u3);
                ay += bf_hi(u0) + bf_hi(u1) + bf_hi(u2) + bf_hi(u3);
            }
            for (; i < n; ++i) {
                int s0 = __shfl(idx, i);
                unsigned int u0 = ((const unsigned int*)(xsb + (size_t)s0 * D_SRC))[lane];
                ax += bf_lo(u0);
                ay += bf_hi(u0);
            }
            if (dtot > CAP) {   // astronomically rare; correctness fallback
                int oc = *ovf_cnt;
                if (oc > OVF_CAP) oc = OVF_CAP;
                for (int o = 0; o < oc; ++o) {
                    if (ovf[2 * o + 1] == node) {
                        int s0 = ovf[2 * o];
                        unsigned int u0 = ((const unsigned int*)(xsb + (size_t)s0 * D_SRC))[lane];
                        ax += bf_lo(u0);
                        ay += bf_hi(u0);
                    }
                }
            }
            float inv = 1.0f / (float)((dtot > 1) ? dtot : 1);
            packed = (unsigned int)f2bf(ax * inv) | ((unsigned int)f2bf(ay * inv) << 16);
        }
        ((unsigned int*)(AsU + nrow * PADA))[lane] = packed;
    }
    __syncthreads();

    // ---- phase 2: MFMA GEMM ----
    int lrow = lane & 15;
    int kq   = lane >> 4;
    int n0 = wave * 64;

    float4v acc[4][4];
    #pragma unroll
    for (int i = 0; i < 4; ++i)
        #pragma unroll
        for (int j = 0; j < 4; ++j)
            acc[i][j] = (float4v){0.f, 0.f, 0.f, 0.f};

    int  rowv[4];
    bool rok[4];
    #pragma unroll
    for (int mf = 0; mf < 4; ++mf) {
        rowv[mf] = m0 + mf * 16 + lrow;
        rok[mf]  = rowv[mf] < N_NODES;
    }
    const short8 zfrag = (short8){0,0,0,0,0,0,0,0};

    #pragma unroll
    for (int kc = 0; kc < 8; ++kc) {
        const int k0 = kc * 32;
        short8 afrag[4], bfrag[4];

        if (kc < 4) {
            #pragma unroll
            for (int mf = 0; mf < 4; ++mf)
                afrag[mf] = rok[mf]
                    ? *(const short8*)(xdb + (size_t)rowv[mf] * D_SRC + k0 + kq * 8)
                    : zfrag;
        } else {
            #pragma unroll
            for (int mf = 0; mf < 4; ++mf)
                afrag[mf] = *(const short8*)&AsU[(mf * 16 + lrow) * PADA + (k0 - 128) + kq * 8];
        }

        #pragma unroll
        for (int nf = 0; nf < 4; ++nf)
            bfrag[nf] = *(const short8*)(Wb + (size_t)(n0 + nf * 16 + lrow) * K_DIM + k0 + kq * 8);

        #pragma unroll
        for (int mf = 0; mf < 4; ++mf)
            #pragma unroll
            for (int nf = 0; nf < 4; ++nf)
                acc[mf][nf] = __builtin_amdgcn_mfma_f32_16x16x32_bf16(
                    afrag[mf], bfrag[nf], acc[mf][nf], 0, 0, 0);
    }
    __syncthreads();   // all LDS A-reads done -> safe to reuse LDS for epilogue

    // ---- epilogue via LDS: bias+relu, 256B-contiguous stores ----
    float* eps = (float*)AsU;   // [4][16][68] floats == 17408 B
    float bv[4];
    #pragma unroll
    for (int nf = 0; nf < 4; ++nf)
        bv[nf] = bias[n0 + nf * 16 + lrow];

    int srow   = lane >> 4;     // 0..3
    int schunk = lane & 15;     // 16B units across 64 cols

    #pragma unroll
    for (int mf = 0; mf < 4; ++mf) {
        #pragma unroll
        for (int nf = 0; nf < 4; ++nf)
            #pragma unroll
            for (int r = 0; r < 4; ++r)
                eps[(wave * 16 + kq * 4 + r) * 68 + nf * 16 + lrow] =
                    fmaxf(acc[mf][nf][r] + bv[nf], 0.f);
        __syncthreads();
        #pragma unroll
        for (int c = 0; c < 4; ++c) {
            int row  = c * 4 + srow;
            float4 v = *(const float4*)&eps[(wave * 16 + row) * 68 + schunk * 4];
            int grow = m0 + mf * 16 + row;
            if (grow < N_NODES)
                *(float4*)(out + (size_t)grow * D_OUT + n0 + schunk * 4) = v;
        }
        __syncthreads();
    }
}

extern "C" void kernel_launch(void* const* d_in, const int* in_sizes, int n_in,
                              void* d_out, int out_size, void* d_ws, size_t ws_size,
                              hipStream_t stream) {
    const float* x_src = (const float*)d_in[0];
    const float* x_dst = (const float*)d_in[1];
    const int*   ei    = (const int*)d_in[2];
    const float* W     = (const float*)d_in[3];
    const float* bias  = (const float*)d_in[4];
    float* out = (float*)d_out;

    int n_edges = in_sizes[2] / 2;

    // workspace layout (16B-aligned):
    //   deg     : N_NODES int            (zeroed)
    //   ovf_cnt : 1 int + 3 pad          (zeroed)
    //   ovf     : OVF_CAP*2 int
    //   bucket  : N_NODES*CAP int
    //   xsb     : N_NODES*128 ushort (bf16 x_src)
    //   xdb     : N_NODES*128 ushort (bf16 x_dst)
    //   Wb      : 256*256 ushort (bf16 W)
    int* deg     = (int*)d_ws;
    int* ovf_cnt = deg + N_NODES;
    int* ovf     = ovf_cnt + 4;
    int* bucket  = ovf + OVF_CAP * 2;
    unsigned short* xsb = (unsigned short*)(bucket + (size_t)N_NODES * CAP);
    unsigned short* xdb = xsb + (size_t)N_NODES * D_SRC;
    unsigned short* Wb  = xdb + (size_t)N_NODES * D_SRC;

    hipMemsetAsync(d_ws, 0, (N_NODES + 4) * sizeof(int), stream);

    int eblocks = (n_edges + 255) / 256;
    int pblocks = (2 * N_NODES * (D_SRC / 4) + (D_OUT * K_DIM) / 4 + 255) / 256;
    bucket_pack_kernel<<<eblocks + pblocks, 256, 0, stream>>>(
        ei, x_src, x_dst, W, deg, ovf_cnt, ovf, bucket, xsb, xdb, Wb,
        n_edges, eblocks);

    fused_gather_gemm_kernel<<<(N_NODES + 63) / 64, 256, 0, stream>>>(
        xsb, xdb, Wb, bias, deg, bucket, ovf_cnt, ovf, out);
}